// Round 4
// baseline (323.592 us; speedup 1.0000x reference)
//
#include <hip/hip_runtime.h>
#include <hip/hip_bf16.h>

#define BB 4
#define TT 4096
#define NTOK (BB * TT)   // 16384
#define DD 1024
#define HH 64
#define NTASK_PB 2176    // tasks per batch (split = 256 cols)
#define NTASK (4 * NTASK_PB)

typedef __attribute__((ext_vector_type(8))) __bf16 bf16x8;
typedef __attribute__((ext_vector_type(8))) unsigned short ushort8;
typedef __attribute__((ext_vector_type(4))) float f32x4;
typedef __attribute__((ext_vector_type(4))) float f4;
typedef unsigned short u16;
typedef unsigned int u32;

__device__ __forceinline__ u16 f2bf(float f) {
  unsigned u = __builtin_bit_cast(unsigned, f);
  u += 0x7FFFu + ((u >> 16) & 1u);   // RNE
  return (u16)(u >> 16);
}
__device__ __forceinline__ float bf2f(u16 s) {
  unsigned u = ((unsigned)s) << 16;
  return __builtin_bit_cast(float, u);
}
__device__ __forceinline__ __bf16 bfbits(u16 s) { return __builtin_bit_cast(__bf16, s); }

__device__ __forceinline__ f32x4 mfma16(bf16x8 a, bf16x8 b, f32x4 c) {
  return __builtin_amdgcn_mfma_f32_16x16x32_bf16(a, b, c, 0, 0, 0);
}

__device__ __forceinline__ u32 cvtpk(float lo, float hi) {
  u32 r;
  asm("v_cvt_pk_bf16_f32 %0, %1, %2" : "=v"(r) : "v"(lo), "v"(hi));
  return r;
}

// ---------------------------------------------------------------------------
// prep_w: W (fp32) -> bf16 hi/lo, plain row-major [64][1024] per array.
// Arrays: 0=Wq_hi 1=Wq_lo 2=Wk_hi 3=Wk_lo 4=Wv_hi, each 65536 u16.
// ---------------------------------------------------------------------------
__global__ __launch_bounds__(256) void prep_w(
    const float* __restrict__ Wq, const float* __restrict__ Wk,
    const float* __restrict__ Wv, u16* __restrict__ wpre)
{
  const int c = blockIdx.x * 256 + threadIdx.x;   // 40960 chunks of 8
  const int arr = c >> 13;
  const int rem = c & 8191;
  const int n = rem >> 7;
  const int j8 = rem & 127;
  const float* W = (arr <= 1) ? Wq : (arr <= 3) ? Wk : Wv;
  const bool lo = (arr == 1) || (arr == 3);
  const float* src = W + (size_t)n * DD + j8 * 8;
  const f4 a = *(const f4*)src;
  const f4 b = *(const f4*)(src + 4);
  ushort8 out;
#pragma unroll
  for (int e = 0; e < 8; ++e) {
    const float f = (e < 4) ? a[e] : b[e - 4];
    const u16 h = f2bf(f);
    out[e] = lo ? f2bf(f - bf2f(h)) : h;
  }
  *(ushort8*)(wpre + (size_t)arr * 65536 + n * 1024 + j8 * 8) = out;
}

// ---------------------------------------------------------------------------
// Projection, barrier-free: no LDS at all. B-fragments (W hi/lo bf16) read
// directly from global (640 KB total, L2-resident); A (x) read f32 + cvt.
// blockIdx = rowblock(256) + 256*type.
// ---------------------------------------------------------------------------
__global__ __launch_bounds__(256) void proj_kernel(
    const float* __restrict__ x,
    const float* __restrict__ bq, const float* __restrict__ bk,
    const float* __restrict__ bv, const u16* __restrict__ wpre,
    u16* __restrict__ qhi, u16* __restrict__ qlo,
    u16* __restrict__ khi, u16* __restrict__ klo,
    u16* __restrict__ vt)
{
  const int tid = threadIdx.x;
  const int w = tid >> 6;
  const int lane = tid & 63;
  const int l15 = lane & 15;
  const int g4 = lane >> 4;
  const int rb = blockIdx.x & 255;
  const int type = blockIdx.x >> 8;
  const bool isv = (type == 2);
  const u16* whiP = wpre + (size_t)((type == 0) ? 0 : (type == 1) ? 2 : 4) * 65536;
  const u16* wloP = whiP + 65536;
  const int mrow = rb * 64 + w * 16 + l15;
  const float* xrow = x + (size_t)mrow * DD;

  f32x4 acc[4];
#pragma unroll
  for (int i = 0; i < 4; ++i) acc[i] = (f32x4){0.f, 0.f, 0.f, 0.f};

#pragma unroll 2
  for (int kt = 0; kt < 16; ++kt) {
    bf16x8 xh[2], xl[2];
#pragma unroll
    for (int ksub = 0; ksub < 2; ++ksub) {
      const float* xs = xrow + kt * 64 + ksub * 32 + g4 * 8;
      const f4 a = *(const f4*)xs;
      const f4 b2 = *(const f4*)(xs + 4);
#pragma unroll
      for (int j = 0; j < 8; ++j) {
        const float f = (j < 4) ? a[j] : b2[j - 4];
        const u16 h = f2bf(f);
        xh[ksub][j] = bfbits(h);
        xl[ksub][j] = bfbits(f2bf(f - bf2f(h)));
      }
    }
#pragma unroll
    for (int ksub = 0; ksub < 2; ++ksub)
#pragma unroll
      for (int nt = 0; nt < 4; ++nt) {
        const u16* wp = whiP + (nt * 16 + l15) * 1024 + kt * 64 + ksub * 32 + g4 * 8;
        const bf16x8 bhi = *(const bf16x8*)wp;
        acc[nt] = mfma16(xh[ksub], bhi, acc[nt]);
        if (!isv) {
          const bf16x8 blo = *(const bf16x8*)(wloP + (nt * 16 + l15) * 1024 +
                                              kt * 64 + ksub * 32 + g4 * 8);
          acc[nt] = mfma16(xh[ksub], blo, acc[nt]);
          acc[nt] = mfma16(xl[ksub], bhi, acc[nt]);
        }
      }
  }
  // epilogue: bias add + hi/lo store
  const float* bias = (type == 0) ? bq : (type == 1) ? bk : bv;
#pragma unroll
  for (int nt = 0; nt < 4; ++nt) {
    const int col = nt * 16 + l15;
    const float bb = bias[col];
#pragma unroll
    for (int rr = 0; rr < 4; ++rr) {
      const int row = rb * 64 + w * 16 + g4 * 4 + rr;
      const float val = acc[nt][rr] + bb;
      const u16 h = f2bf(val);
      if (type == 0) {
        qhi[(size_t)row * HH + col] = h;
        qlo[(size_t)row * HH + col] = f2bf(val - bf2f(h));
      } else if (type == 1) {
        khi[(size_t)row * HH + col] = h;
        klo[(size_t)row * HH + col] = f2bf(val - bf2f(h));
      } else {
        vt[(size_t)col * NTOK + row] = h;
      }
    }
  }
}

// ---------------------------------------------------------------------------
// Flash attention (roles swapped), swapped-operand QK^T so each lane owns a
// full S row (i = lane&15): softmax = in-lane reduce + 2 shuffles.
// BC=128 per iteration, <=2 iterations per task (256-col splits).
// Task t (per batch): group g = tw>>4 has ns = g+1 splits;
// base(g) = 8g(g+1); t = base + tile*(g+1) + s; tw = g*16+tile.
// Partials: Opart bf16 [task][h=64][i=16]; ml f32 m then l.
// ---------------------------------------------------------------------------
__global__ __launch_bounds__(256) void attn_kernel(
    const u16* __restrict__ qhi, const u16* __restrict__ qlo,
    const u16* __restrict__ khi, const u16* __restrict__ klo,
    const u16* __restrict__ vt, u16* __restrict__ Opart,
    float* __restrict__ ml)
{
  __shared__ __attribute__((aligned(16))) u16 plds[4][16][136];
  const int tid = threadIdx.x;
  const int lane = tid & 63;
  const int w = tid >> 6;
  const int l15 = lane & 15;
  const int g4 = lane >> 4;

  const int task = blockIdx.x * 4 + w;     // < 8704
  const int b = task / NTASK_PB;
  const int t = task - b * NTASK_PB;
  int g = 0;
#pragma unroll
  for (int gg = 1; gg < 16; ++gg)
    if (t >= 8 * gg * (gg + 1)) g = gg;
  const int r = t - 8 * g * (g + 1);
  const int den = g + 1;
  const int tile = r / den;
  const int s = r - tile * den;
  const int tw = g * 16 + tile;
  const int rowbase = tw * 16;
  const int njt64 = (tw >> 2) + 1;
  const int njt128 = (njt64 + 1) >> 1;
  const int jt0 = s * 2;
  const int jtend = (jt0 + 2 < njt128) ? jt0 + 2 : njt128;

  const u16* qhb = qhi + (size_t)b * TT * HH;
  const u16* qlb = qlo + (size_t)b * TT * HH;
  const u16* vtb = vt + (size_t)b * TT;

  // hoisted roleQ (k-proj) B-fragments
  bf16x8 kh[2], kl2[2];
  {
    const size_t koff = (size_t)(b * TT + rowbase + l15) * HH + g4 * 8;
    kh[0] = *(const bf16x8*)(khi + koff);
    kh[1] = *(const bf16x8*)(khi + koff + 32);
    kl2[0] = *(const bf16x8*)(klo + koff);
    kl2[1] = *(const bf16x8*)(klo + koff + 32);
  }

  float m = -INFINITY, lsum = 0.f;     // per-lane: row i = rowbase + l15
  f32x4 O[4];
#pragma unroll
  for (int ht = 0; ht < 4; ++ht) O[ht] = (f32x4){0.f, 0.f, 0.f, 0.f};

  for (int jt = jt0; jt < jtend; ++jt) {
    const int j0 = jt * 128;
    f32x4 S[8];
#pragma unroll
    for (int nt = 0; nt < 8; ++nt) S[nt] = (f32x4){0.f, 0.f, 0.f, 0.f};
#pragma unroll
    for (int nt = 0; nt < 8; ++nt) {
      const int qo = (j0 + nt * 16 + l15) * HH + g4 * 8;
      const bf16x8 q0 = *(const bf16x8*)(qhb + qo);
      const bf16x8 q1 = *(const bf16x8*)(qhb + qo + 32);
      const bf16x8 ql0 = *(const bf16x8*)(qlb + qo);
      const bf16x8 ql1 = *(const bf16x8*)(qlb + qo + 32);
      S[nt] = mfma16(q0, kh[0], S[nt]);
      S[nt] = mfma16(q1, kh[1], S[nt]);
      S[nt] = mfma16(ql0, kh[0], S[nt]);
      S[nt] = mfma16(ql1, kh[1], S[nt]);
      S[nt] = mfma16(q0, kl2[0], S[nt]);
      S[nt] = mfma16(q1, kl2[1], S[nt]);
    }
    if (jt == njt128 - 1) {  // diagonal tile: mask j > i
      const int ii = rowbase + l15;
#pragma unroll
      for (int nt = 0; nt < 8; ++nt)
#pragma unroll
        for (int rr = 0; rr < 4; ++rr) {
          const int jj = j0 + nt * 16 + g4 * 4 + rr;
          if (jj > ii) S[nt][rr] = -INFINITY;
        }
    }
    // row softmax: in-lane over 32 values + 2 cross-lane shuffles
    float tm = -INFINITY;
#pragma unroll
    for (int nt = 0; nt < 8; ++nt)
#pragma unroll
      for (int rr = 0; rr < 4; ++rr) tm = fmaxf(tm, S[nt][rr]);
    tm = fmaxf(tm, __shfl_xor(tm, 16));
    tm = fmaxf(tm, __shfl_xor(tm, 32));
    const float mnew = fmaxf(m, tm);
    const float sc = __expf(m - mnew);
    m = mnew;
    float ssum = 0.f;
#pragma unroll
    for (int nt = 0; nt < 8; ++nt)
#pragma unroll
      for (int rr = 0; rr < 4; ++rr) {
        const float p = __expf(S[nt][rr] - mnew);
        S[nt][rr] = p;
        ssum += p;
      }
    ssum += __shfl_xor(ssum, 16);
    ssum += __shfl_xor(ssum, 32);
    lsum = lsum * sc + ssum;
#pragma unroll
    for (int ht = 0; ht < 4; ++ht)
#pragma unroll
      for (int rr = 0; rr < 4; ++rr) O[ht][rr] *= sc;
    // P -> LDS transposed store [i][j] via packed b32 (wave-private)
#pragma unroll
    for (int nt = 0; nt < 8; ++nt) {
      const u32 w0 = cvtpk(S[nt][0], S[nt][1]);
      const u32 w1 = cvtpk(S[nt][2], S[nt][3]);
      *(u32*)&plds[w][l15][nt * 16 + g4 * 4] = w0;
      *(u32*)&plds[w][l15][nt * 16 + g4 * 4 + 2] = w1;
    }
    // PV: A = v^T rows (h), B = P_T from LDS
#pragma unroll
    for (int kt2 = 0; kt2 < 4; ++kt2) {
      const bf16x8 pf = *(const bf16x8*)&plds[w][l15][kt2 * 32 + g4 * 8];
#pragma unroll
      for (int ht = 0; ht < 4; ++ht) {
        const bf16x8 vf = *(const bf16x8*)(vtb + (size_t)(ht * 16 + l15) * NTOK +
                                           j0 + kt2 * 32 + g4 * 8);
        O[ht] = mfma16(vf, pf, O[ht]);
      }
    }
  }
  // epilogue: bf16 partials [task][h][i]
  u16* opb = Opart + (size_t)task * 1024;
#pragma unroll
  for (int ht = 0; ht < 4; ++ht)
#pragma unroll
    for (int rr = 0; rr < 4; ++rr)
      opb[(ht * 16 + g4 * 4 + rr) * 16 + l15] = f2bf(O[ht][rr]);
  if (g4 == 0) {
    ml[task * 16 + l15] = m;
    ml[NTASK * 16 + task * 16 + l15] = lsum;
  }
}

// ---------------------------------------------------------------------------
// Combine: one block per (b, tw); merge ns = (tw>>4)+1 split partials,
// normalize, LDS-transpose, coalesced fp32 store.
// ---------------------------------------------------------------------------
__global__ __launch_bounds__(256) void combine_kernel(
    const u16* __restrict__ Opart, const float* __restrict__ ml,
    float* __restrict__ out)
{
  __shared__ float lt[16][68];
  const int tid = threadIdx.x;
  const int b = blockIdx.x >> 8;
  const int tw = blockIdx.x & 255;
  const int g = tw >> 4;
  const int tile = tw & 15;
  const int base_task = b * NTASK_PB + 8 * g * (g + 1) + tile * (g + 1);
  const int ns = g + 1;
  const int ro = tid & 15;
  const int hq = tid >> 4;   // 16 groups of 4 h
  const float* mb = ml;
  const float* lb = ml + NTASK * 16;

  float M = -INFINITY;
  for (int s = 0; s < ns; ++s)
    M = fmaxf(M, mb[(base_task + s) * 16 + ro]);
  float L = 0.f;
  float acc[4] = {0.f, 0.f, 0.f, 0.f};
  for (int s = 0; s < ns; ++s) {
    const int task = base_task + s;
    const float e = __expf(mb[task * 16 + ro] - M);
    L += e * lb[task * 16 + ro];
#pragma unroll
    for (int et = 0; et < 4; ++et)
      acc[et] += e * bf2f(Opart[(size_t)task * 1024 + (hq * 4 + et) * 16 + ro]);
  }
#pragma unroll
  for (int et = 0; et < 4; ++et) lt[ro][hq * 4 + et] = acc[et] / L;
  __syncthreads();
  const int h2 = tid & 63;
  const int iq = tid >> 6;
#pragma unroll
  for (int pp = 0; pp < 4; ++pp) {
    const int i = iq * 4 + pp;
    out[(size_t)(b * TT + tw * 16 + i) * HH + h2] = lt[i][h2];
  }
}

extern "C" void kernel_launch(void* const* d_in, const int* in_sizes, int n_in,
                              void* d_out, int out_size, void* d_ws, size_t ws_size,
                              hipStream_t stream) {
  (void)in_sizes; (void)n_in; (void)out_size; (void)ws_size;
  const float* x  = (const float*)d_in[0];
  const float* Wq = (const float*)d_in[1];
  const float* bq = (const float*)d_in[2];
  const float* Wk = (const float*)d_in[3];
  const float* bk = (const float*)d_in[4];
  const float* Wv = (const float*)d_in[5];
  const float* bv = (const float*)d_in[6];
  float* out = (float*)d_out;

  u16* ws   = (u16*)d_ws;
  u16* wpre = ws;                          // 5*65536 u16
  u16* qhi  = ws + 5 * 65536;
  u16* qlo  = qhi + (size_t)NTOK * HH;
  u16* khi  = qlo + (size_t)NTOK * HH;
  u16* klo  = khi + (size_t)NTOK * HH;
  u16* vt   = klo + (size_t)NTOK * HH;     // [64][NTOK]
  u16* Opart = vt + (size_t)NTOK * HH;     // NTASK*1024 u16
  float* ml  = (float*)(Opart + (size_t)NTASK * 1024);  // 2*NTASK*16 f32

  prep_w<<<160, 256, 0, stream>>>(Wq, Wk, Wv, wpre);
  proj_kernel<<<768, 256, 0, stream>>>(x, bq, bk, bv, wpre,
                                       qhi, qlo, khi, klo, vt);
  attn_kernel<<<NTASK / 4, 256, 0, stream>>>(qhi, qlo, khi, klo, vt, Opart, ml);
  combine_kernel<<<1024, 256, 0, stream>>>(Opart, ml, out);
}

// Round 6
// 273.065 us; speedup vs baseline: 1.1850x; 1.1850x over previous
//
#include <hip/hip_runtime.h>
#include <hip/hip_bf16.h>

#define BB 4
#define TT 4096
#define NTOK (BB * TT)   // 16384
#define DD 1024
#define HH 64
#define NTASKS 2048      // 4 b x 64 TW x 8 s (some empty)

typedef __attribute__((ext_vector_type(8))) __bf16 bf16x8;
typedef __attribute__((ext_vector_type(8))) unsigned short ushort8;
typedef __attribute__((ext_vector_type(4))) float f32x4;
typedef __attribute__((ext_vector_type(4))) float f4;
typedef unsigned short u16;
typedef unsigned int u32;

__device__ __forceinline__ u16 f2bf(float f) {
  unsigned u = __builtin_bit_cast(unsigned, f);
  u += 0x7FFFu + ((u >> 16) & 1u);   // RNE
  return (u16)(u >> 16);
}
__device__ __forceinline__ float bf2f(u16 s) {
  unsigned u = ((unsigned)s) << 16;
  return __builtin_bit_cast(float, u);
}
__device__ __forceinline__ f32x4 mfma16(bf16x8 a, bf16x8 b, f32x4 c) {
  return __builtin_amdgcn_mfma_f32_16x16x32_bf16(a, b, c, 0, 0, 0);
}
__device__ __forceinline__ u32 cvtpk(float lo, float hi) {
  u32 r;
  asm("v_cvt_pk_bf16_f32 %0, %1, %2" : "=v"(r) : "v"(lo), "v"(hi));
  return r;
}
// pack upper-16s of two floats: (hi16(f1)<<16)|hi16(f0)  -- truncating bf16 pair
__device__ __forceinline__ u32 permhi(u32 u1, u32 u0) {
  return __builtin_amdgcn_perm(u1, u0, 0x07060302u);
}
__device__ __forceinline__ void gl_lds16(const u16* g, u16* l) {
  __builtin_amdgcn_global_load_lds(
      (const __attribute__((address_space(1))) u32*)(const void*)g,
      (__attribute__((address_space(3))) u32*)(void*)l, 16, 0, 0);
}

// ---------------------------------------------------------------------------
// prep_w: W (fp32) -> bf16 hi/lo in FRAGMENT-LINEAR order:
// [kt(16)][ksub(2)][nt(4)][lane(64)][e(8)] so proj's B-operand load is one
// coalesced dwordx4 per lane. frag elem: W[nt*16+(l&15)][kt*64+ksub*32+(l>>4)*8+e]
// Arrays: 0=Wq_hi 1=Wq_lo 2=Wk_hi 3=Wk_lo 4=Wv_hi, each 65536 u16.
// ---------------------------------------------------------------------------
__global__ __launch_bounds__(256) void prep_w(
    const float* __restrict__ Wq, const float* __restrict__ Wk,
    const float* __restrict__ Wv, u16* __restrict__ wpre)
{
  const int c = blockIdx.x * 256 + threadIdx.x;   // 40960 ushort8 chunks
  const int arr = c >> 13;
  const int rem = c & 8191;      // [kt][ksub][nt][lane]
  const int lane = rem & 63;
  const int nt = (rem >> 6) & 3;
  const int ksub = (rem >> 8) & 1;
  const int kt = rem >> 9;
  const float* W = (arr <= 1) ? Wq : (arr <= 3) ? Wk : Wv;
  const bool lo = (arr == 1) || (arr == 3);
  const int n = nt * 16 + (lane & 15);
  const int k0 = kt * 64 + ksub * 32 + (lane >> 4) * 8;
  const float* src = W + (size_t)n * DD + k0;
  ushort8 out;
#pragma unroll
  for (int e = 0; e < 8; ++e) {
    const float f = src[e];
    const u16 h = f2bf(f);
    out[e] = lo ? f2bf(f - bf2f(h)) : h;
  }
  *(ushort8*)(wpre + (size_t)arr * 65536 + (size_t)rem * 8) = out;
}

// ---------------------------------------------------------------------------
// Projection: barrier-free, LDS-free. W via coalesced fragment-linear loads
// (L2-resident 640KB). x split hi/lo by truncation (v_perm, cheap); residual
// captured exactly by lo so precision matches RNE hi/lo. blockIdx =
// rowblock(256) + 256*type. q/k stores column-chunk-swizzled: c ^= (row&7).
// ---------------------------------------------------------------------------
__global__ __launch_bounds__(256) void proj_kernel(
    const float* __restrict__ x,
    const float* __restrict__ bq, const float* __restrict__ bk,
    const float* __restrict__ bv, const u16* __restrict__ wpre,
    u16* __restrict__ qhi, u16* __restrict__ qlo,
    u16* __restrict__ khi, u16* __restrict__ klo,
    u16* __restrict__ vt)
{
  const int tid = threadIdx.x;
  const int w = tid >> 6;
  const int lane = tid & 63;
  const int l15 = lane & 15;
  const int g4 = lane >> 4;
  const int rb = blockIdx.x & 255;
  const int type = blockIdx.x >> 8;
  const bool isv = (type == 2);
  const u16* whiP = wpre + (size_t)((type == 0) ? 0 : (type == 1) ? 2 : 4) * 65536;
  const int mrow = rb * 64 + w * 16 + l15;
  const float* xrow = x + (size_t)mrow * DD;

  f32x4 acc[4];
#pragma unroll
  for (int i = 0; i < 4; ++i) acc[i] = (f32x4){0.f, 0.f, 0.f, 0.f};

  for (int kt = 0; kt < 16; ++kt) {
#pragma unroll
    for (int ksub = 0; ksub < 2; ++ksub) {
      const float* xs = xrow + kt * 64 + ksub * 32 + g4 * 8;
      const f4 a = *(const f4*)xs;
      const f4 b2 = *(const f4*)(xs + 4);
      u32 xh32[4], xl32[4];
#pragma unroll
      for (int p = 0; p < 4; ++p) {
        const float f0 = (p < 2) ? a[2 * p] : b2[2 * p - 4];
        const float f1 = (p < 2) ? a[2 * p + 1] : b2[2 * p - 3];
        const u32 u0 = __builtin_bit_cast(u32, f0);
        const u32 u1 = __builtin_bit_cast(u32, f1);
        xh32[p] = permhi(u1, u0);
        const float h0 = __builtin_bit_cast(float, u0 & 0xFFFF0000u);
        const float h1 = __builtin_bit_cast(float, u1 & 0xFFFF0000u);
        const u32 v0 = __builtin_bit_cast(u32, f0 - h0);
        const u32 v1 = __builtin_bit_cast(u32, f1 - h1);
        xl32[p] = permhi(v1, v0);
      }
      bf16x8 xh, xl;
#pragma unroll
      for (int p = 0; p < 4; ++p) {
        ((u32*)&xh)[p] = xh32[p];
        ((u32*)&xl)[p] = xl32[p];
      }
      const u16* fb = whiP + ((kt * 2 + ksub) * 4) * 512 + lane * 8;
#pragma unroll
      for (int nt = 0; nt < 4; ++nt) {
        const bf16x8 bhi = *(const bf16x8*)(fb + nt * 512);
        acc[nt] = mfma16(xh, bhi, acc[nt]);
        if (!isv) {
          const bf16x8 blo = *(const bf16x8*)(fb + 65536 + nt * 512);
          acc[nt] = mfma16(xh, blo, acc[nt]);
          acc[nt] = mfma16(xl, bhi, acc[nt]);
        }
      }
    }
  }
  // epilogue: bias add + hi/lo store (q/k chunk-swizzled for attn LDS staging)
  const float* bias = (type == 0) ? bq : (type == 1) ? bk : bv;
#pragma unroll
  for (int nt = 0; nt < 4; ++nt) {
    const int col = nt * 16 + l15;
    const float bb = bias[col];
#pragma unroll
    for (int rr = 0; rr < 4; ++rr) {
      const int row = rb * 64 + w * 16 + g4 * 4 + rr;
      const float val = acc[nt][rr] + bb;
      const u16 h = f2bf(val);
      if (type < 2) {
        const int colS = ((((col >> 3) ^ (row & 7)) << 3) | (col & 7));
        u16* hiP = (type == 0) ? qhi : khi;
        u16* loP = (type == 0) ? qlo : klo;
        hiP[(size_t)row * HH + colS] = h;
        loP[(size_t)row * HH + colS] = f2bf(val - bf2f(h));
      } else {
        vt[(size_t)col * NTOK + row] = h;
      }
    }
  }
}

// ---------------------------------------------------------------------------
// Flash attention (roles swapped), block-cooperative:
// block = (b, TW 64-row tile, split s of 8 j-tiles x 64 cols). 4 waves, wave w
// owns rows TW*64 + w*16 .. +16. Q hi/lo staged (double-buffered) in LDS via
// VERBATIM copy of the already-swizzled global array (global_load_lds linear
// dest) -- LDS inherits the swizzle; ds_reads XOR-decode it exactly once.
// V direct (same addrs across waves -> L1). Swapped-operand QK^T: lane owns a
// full S row. ns(TW) = (TW+8)>>3; blocks with s >= ns exit.
// ---------------------------------------------------------------------------
__global__ __launch_bounds__(256) void attn_kernel(
    const u16* __restrict__ qhi, const u16* __restrict__ qlo,
    const u16* __restrict__ khi, const u16* __restrict__ klo,
    const u16* __restrict__ vt, u16* __restrict__ Opart,
    float* __restrict__ ml)
{
  __shared__ __attribute__((aligned(16))) u16 qh_lds[2][64][64];
  __shared__ __attribute__((aligned(16))) u16 ql_lds[2][64][64];
  __shared__ __attribute__((aligned(16))) u16 plds[4][16][72];
  const int tid = threadIdx.x;
  const int lane = tid & 63;
  const int w = tid >> 6;
  const int l15 = lane & 15;
  const int g4 = lane >> 4;

  const int b = blockIdx.x >> 9;
  const int TW = (blockIdx.x >> 3) & 63;
  const int s = blockIdx.x & 7;
  const int ns = (TW + 8) >> 3;          // ceil((TW+1)/8)
  if (s >= ns) return;
  const int jt0 = s * 8;
  const int jt1 = (jt0 + 8 < TW + 1) ? jt0 + 8 : TW + 1;
  const int rowbase = TW * 64 + w * 16;

  // K fragments (roleQ = k-proj), swizzled addressing: chunk ^= (l15&7)
  bf16x8 kh[2], kl[2];
#pragma unroll
  for (int ksub = 0; ksub < 2; ++ksub) {
    const size_t ro = (size_t)(b * TT + rowbase + l15) * HH;
    const int ch = ((ksub * 4 + g4) ^ (l15 & 7)) * 8;
    kh[ksub] = *(const bf16x8*)(khi + ro + ch);
    kl[ksub] = *(const bf16x8*)(klo + ro + ch);
  }

  // stage j-tile jt into buffer buf: VERBATIM row copy (swizzle preserved)
  auto stage = [&](int buf, int jt) {
    const size_t gbase = (size_t)(b * TT + jt * 64) * HH;
    const int rsrc = (lane >> 3);
    const int csrc = (lane & 7) * 8;     // linear copy; swizzle lives in data
#pragma unroll
    for (int i = 0; i < 2; ++i) {
      const int r0 = w * 16 + i * 8;
      const size_t src = gbase + (size_t)(r0 + rsrc) * HH + csrc;
      gl_lds16(qhi + src, &qh_lds[buf][r0][0]);
      gl_lds16(qlo + src, &ql_lds[buf][r0][0]);
    }
  };

  float m = -INFINITY, lsum = 0.f;       // per-lane row i = rowbase + l15
  f32x4 O[4];
#pragma unroll
  for (int ht = 0; ht < 4; ++ht) O[ht] = (f32x4){0.f, 0.f, 0.f, 0.f};

  stage(0, jt0);
  __syncthreads();
  int cur = 0;
  for (int jt = jt0; jt < jt1; ++jt) {
    if (jt + 1 < jt1) stage(cur ^ 1, jt + 1);
    // ---- QK^T (swapped): S[nt] cols i=l15, rows j = nt*16 + g4*4 + rr ----
    f32x4 S[4];
#pragma unroll
    for (int nt = 0; nt < 4; ++nt) S[nt] = (f32x4){0.f, 0.f, 0.f, 0.f};
#pragma unroll
    for (int nt = 0; nt < 4; ++nt) {
      const int row = nt * 16 + l15;
      const int c0 = (g4 ^ (l15 & 7)) * 8;
      const int c1 = ((4 + g4) ^ (l15 & 7)) * 8;
      const bf16x8 q0 = *(const bf16x8*)&qh_lds[cur][row][c0];
      const bf16x8 q1 = *(const bf16x8*)&qh_lds[cur][row][c1];
      const bf16x8 ql0 = *(const bf16x8*)&ql_lds[cur][row][c0];
      const bf16x8 ql1 = *(const bf16x8*)&ql_lds[cur][row][c1];
      S[nt] = mfma16(q0, kh[0], S[nt]);
      S[nt] = mfma16(q1, kh[1], S[nt]);
      S[nt] = mfma16(ql0, kh[0], S[nt]);
      S[nt] = mfma16(ql1, kh[1], S[nt]);
      S[nt] = mfma16(q0, kl[0], S[nt]);
      S[nt] = mfma16(q1, kl[1], S[nt]);
    }
    if (jt == TW) {  // diagonal tile: mask j > i
      const int ii = rowbase + l15;
#pragma unroll
      for (int nt = 0; nt < 4; ++nt)
#pragma unroll
        for (int rr = 0; rr < 4; ++rr) {
          const int jj = jt * 64 + nt * 16 + g4 * 4 + rr;
          if (jj > ii) S[nt][rr] = -INFINITY;
        }
    }
    // ---- online softmax: 16 in-lane values + 2 shuffles ----
    float tm = -INFINITY;
#pragma unroll
    for (int nt = 0; nt < 4; ++nt)
#pragma unroll
      for (int rr = 0; rr < 4; ++rr) tm = fmaxf(tm, S[nt][rr]);
    tm = fmaxf(tm, __shfl_xor(tm, 16));
    tm = fmaxf(tm, __shfl_xor(tm, 32));
    const float mnew = fmaxf(m, tm);
    const float sc = __expf(m - mnew);
    m = mnew;
    float ssum = 0.f;
#pragma unroll
    for (int nt = 0; nt < 4; ++nt)
#pragma unroll
      for (int rr = 0; rr < 4; ++rr) {
        const float p = __expf(S[nt][rr] - mnew);
        S[nt][rr] = p;
        ssum += p;
      }
    ssum += __shfl_xor(ssum, 16);
    ssum += __shfl_xor(ssum, 32);
    lsum = lsum * sc + ssum;
#pragma unroll
    for (int ht = 0; ht < 4; ++ht)
#pragma unroll
      for (int rr = 0; rr < 4; ++rr) O[ht][rr] *= sc;
    // ---- P -> wave-private LDS (packed bf16), re-layout for PV B-operand ----
#pragma unroll
    for (int nt = 0; nt < 4; ++nt) {
      *(u32*)&plds[w][l15][nt * 16 + g4 * 4] = cvtpk(S[nt][0], S[nt][1]);
      *(u32*)&plds[w][l15][nt * 16 + g4 * 4 + 2] = cvtpk(S[nt][2], S[nt][3]);
    }
    // ---- PV: A = v^T row h (direct global, L1-shared), B = P^T from LDS ----
    const int j0 = jt * 64;
#pragma unroll
    for (int kt2 = 0; kt2 < 2; ++kt2) {
      const bf16x8 pf = *(const bf16x8*)&plds[w][l15][kt2 * 32 + g4 * 8];
#pragma unroll
      for (int ht = 0; ht < 4; ++ht) {
        const u16* vp = vt + (size_t)(ht * 16 + l15) * NTOK + b * TT + j0 +
                        kt2 * 32 + g4 * 8;
        O[ht] = mfma16(*(const bf16x8*)vp, pf, O[ht]);
      }
    }
    __syncthreads();
    cur ^= 1;
  }
  // epilogue: partials Opart[task][h=64][r=64] bf16; ml m/l per row
  const int task = blockIdx.x;
  u16* opb = Opart + (size_t)task * 4096;
#pragma unroll
  for (int ht = 0; ht < 4; ++ht)
#pragma unroll
    for (int rr = 0; rr < 4; ++rr)
      opb[(ht * 16 + g4 * 4 + rr) * 64 + w * 16 + l15] = f2bf(O[ht][rr]);
  if (g4 == 0) {
    ml[task * 64 + w * 16 + l15] = m;
    ml[NTASKS * 64 + task * 64 + w * 16 + l15] = lsum;
  }
}

// ---------------------------------------------------------------------------
// Combine: block per (b, TW); merge ns split partials, normalize, LDS
// transpose, coalesced fp32 store.
// ---------------------------------------------------------------------------
__global__ __launch_bounds__(256) void combine_kernel(
    const u16* __restrict__ Opart, const float* __restrict__ ml,
    float* __restrict__ out)
{
  __shared__ float lt[64][65];
  const int tid = threadIdx.x;
  const int b = blockIdx.x >> 6;
  const int TW = blockIdx.x & 63;
  const int ns = (TW + 8) >> 3;
  const int tb = blockIdx.x * 8;       // task base
  const int ro = tid & 63;
  const int hq = tid >> 6;             // 4 h-groups of 16
  const float* mb = ml;
  const float* lb = ml + NTASKS * 64;

  float M = -INFINITY;
  for (int ss = 0; ss < ns; ++ss)
    M = fmaxf(M, mb[(tb + ss) * 64 + ro]);
  float L = 0.f;
  float acc[16];
#pragma unroll
  for (int hh = 0; hh < 16; ++hh) acc[hh] = 0.f;
  for (int ss = 0; ss < ns; ++ss) {
    const float e = __expf(mb[(tb + ss) * 64 + ro] - M);
    L += e * lb[(tb + ss) * 64 + ro];
    const u16* op = Opart + (size_t)(tb + ss) * 4096 + hq * 16 * 64 + ro;
#pragma unroll
    for (int hh = 0; hh < 16; ++hh) acc[hh] += e * bf2f(op[hh * 64]);
  }
  const float rL = 1.f / L;
#pragma unroll
  for (int hh = 0; hh < 16; ++hh) lt[ro][hq * 16 + hh] = acc[hh] * rL;
  __syncthreads();
  const int h2 = tid & 63;
  const int rq = tid >> 6;
#pragma unroll
  for (int pp = 0; pp < 16; ++pp) {
    const int r = rq * 16 + pp;
    out[(size_t)(b * TT + TW * 64 + r) * HH + h2] = lt[r][h2];
  }
}

extern "C" void kernel_launch(void* const* d_in, const int* in_sizes, int n_in,
                              void* d_out, int out_size, void* d_ws, size_t ws_size,
                              hipStream_t stream) {
  (void)in_sizes; (void)n_in; (void)out_size; (void)ws_size;
  const float* x  = (const float*)d_in[0];
  const float* Wq = (const float*)d_in[1];
  const float* bq = (const float*)d_in[2];
  const float* Wk = (const float*)d_in[3];
  const float* bk = (const float*)d_in[4];
  const float* Wv = (const float*)d_in[5];
  const float* bv = (const float*)d_in[6];
  float* out = (float*)d_out;

  u16* ws   = (u16*)d_ws;
  u16* wpre = ws;                          // 5*65536 u16
  u16* qhi  = ws + 5 * 65536;
  u16* qlo  = qhi + (size_t)NTOK * HH;
  u16* khi  = qlo + (size_t)NTOK * HH;
  u16* klo  = khi + (size_t)NTOK * HH;
  u16* vt   = klo + (size_t)NTOK * HH;     // [64][NTOK]
  u16* Opart = vt + (size_t)NTOK * HH;     // NTASKS*4096 u16
  float* ml  = (float*)(Opart + (size_t)NTASKS * 4096);  // 2*NTASKS*64 f32

  prep_w<<<160, 256, 0, stream>>>(Wq, Wk, Wv, wpre);
  proj_kernel<<<768, 256, 0, stream>>>(x, bq, bk, bv, wpre,
                                       qhi, qlo, khi, klo, vt);
  attn_kernel<<<NTASKS, 256, 0, stream>>>(qhi, qlo, khi, klo, vt, Opart, ml);
  combine_kernel<<<256, 256, 0, stream>>>(Opart, ml, out);
}

// Round 9
// 235.800 us; speedup vs baseline: 1.3723x; 1.1580x over previous
//
#include <hip/hip_runtime.h>
#include <hip/hip_bf16.h>

#define BB 4
#define TT 4096
#define NTOK (BB * TT)   // 16384
#define DD 1024
#define HH 64
#define NTASKS 2048      // 4 b x 64 TW x 8 s (some empty)

typedef __attribute__((ext_vector_type(8))) __bf16 bf16x8;
typedef __attribute__((ext_vector_type(8))) unsigned short ushort8;
typedef __attribute__((ext_vector_type(4))) float f32x4;
typedef __attribute__((ext_vector_type(4))) float f4;
typedef unsigned short u16;
typedef unsigned int u32;

__device__ __forceinline__ u16 f2bf(float f) {
  unsigned u = __builtin_bit_cast(unsigned, f);
  u += 0x7FFFu + ((u >> 16) & 1u);   // RNE
  return (u16)(u >> 16);
}
__device__ __forceinline__ float bf2f(u16 s) {
  unsigned u = ((unsigned)s) << 16;
  return __builtin_bit_cast(float, u);
}
__device__ __forceinline__ f32x4 mfma16(bf16x8 a, bf16x8 b, f32x4 c) {
  return __builtin_amdgcn_mfma_f32_16x16x32_bf16(a, b, c, 0, 0, 0);
}
__device__ __forceinline__ u32 cvtpk(float lo, float hi) {
  u32 r;
  asm("v_cvt_pk_bf16_f32 %0, %1, %2" : "=v"(r) : "v"(lo), "v"(hi));
  return r;
}
// pack upper-16s of two floats: (hi16(f1)<<16)|hi16(f0)  -- truncating bf16 pair
__device__ __forceinline__ u32 permhi(u32 u1, u32 u0) {
  return __builtin_amdgcn_perm(u1, u0, 0x07060302u);
}
__device__ __forceinline__ void gl_lds16(const u16* g, u16* l) {
  __builtin_amdgcn_global_load_lds(
      (const __attribute__((address_space(1))) u32*)(const void*)g,
      (__attribute__((address_space(3))) u32*)(void*)l, 16, 0, 0);
}

// ---------------------------------------------------------------------------
// prep_w: W (fp32) -> bf16 hi/lo in FRAGMENT-LINEAR order:
// [kt(16)][ksub(2)][nt(4)][lane(64)][e(8)] so proj's B-operand load is one
// coalesced dwordx4 per lane. frag elem: W[nt*16+(l&15)][kt*64+ksub*32+(l>>4)*8+e]
// Arrays: 0=Wq_hi 1=Wq_lo 2=Wk_hi 3=Wk_lo 4=Wv_hi, each 65536 u16.
// ---------------------------------------------------------------------------
__global__ __launch_bounds__(256) void prep_w(
    const float* __restrict__ Wq, const float* __restrict__ Wk,
    const float* __restrict__ Wv, u16* __restrict__ wpre)
{
  const int c = blockIdx.x * 256 + threadIdx.x;   // 40960 ushort8 chunks
  const int arr = c >> 13;
  const int rem = c & 8191;      // [kt][ksub][nt][lane]
  const int lane = rem & 63;
  const int nt = (rem >> 6) & 3;
  const int ksub = (rem >> 8) & 1;
  const int kt = rem >> 9;
  const float* W = (arr <= 1) ? Wq : (arr <= 3) ? Wk : Wv;
  const bool lo = (arr == 1) || (arr == 3);
  const int n = nt * 16 + (lane & 15);
  const int k0 = kt * 64 + ksub * 32 + (lane >> 4) * 8;
  const float* src = W + (size_t)n * DD + k0;
  ushort8 out;
#pragma unroll
  for (int e = 0; e < 8; ++e) {
    const float f = src[e];
    const u16 h = f2bf(f);
    out[e] = lo ? f2bf(f - bf2f(h)) : h;
  }
  *(ushort8*)(wpre + (size_t)arr * 65536 + (size_t)rem * 8) = out;
}

// ---------------------------------------------------------------------------
// Projection: barrier-free, LDS-free, SOFTWARE-PIPELINED. W via coalesced
// fragment-linear loads (L2-resident); x split hi/lo by truncation (v_perm).
// Register double-buffer A/B: loads for iteration it+1 are issued before the
// MFMAs of iteration it. __launch_bounds__(256,3): allow ~168 VGPR while
// keeping 3 blocks/CU. blockIdx = rowblock(256) + 256*type.
// q/k stores column-chunk-swizzled: chunk ^= (row&7).
// ---------------------------------------------------------------------------
__global__ __launch_bounds__(256, 3) void proj_kernel(
    const float* __restrict__ x,
    const float* __restrict__ bq, const float* __restrict__ bk,
    const float* __restrict__ bv, const u16* __restrict__ wpre,
    u16* __restrict__ qhi, u16* __restrict__ qlo,
    u16* __restrict__ khi, u16* __restrict__ klo,
    u16* __restrict__ vt)
{
  const int tid = threadIdx.x;
  const int w = tid >> 6;
  const int lane = tid & 63;
  const int l15 = lane & 15;
  const int g4 = lane >> 4;
  const int rb = blockIdx.x & 255;
  const int type = blockIdx.x >> 8;
  const bool isv = (type == 2);
  const u16* whiP = wpre + (size_t)((type == 0) ? 0 : (type == 1) ? 2 : 4) * 65536;
  const int mrow = rb * 64 + w * 16 + l15;
  const float* xrow = x + (size_t)mrow * DD;

  f32x4 acc[4];
#pragma unroll
  for (int i = 0; i < 4; ++i) acc[i] = (f32x4){0.f, 0.f, 0.f, 0.f};

  // named double-buffers (static allocation; no runtime indexing)
  f4 xaA, xbA, xaB, xbB;
  bf16x8 whA[4], wlA[4], whB[4], wlB[4];

#define LOAD_ITER(XA, XB, WH, WL, IT)                                         \
  {                                                                           \
    const float* xs_ = xrow + (IT) * 32 + g4 * 8;                             \
    XA = *(const f4*)xs_;                                                     \
    XB = *(const f4*)(xs_ + 4);                                               \
    const u16* fb_ = whiP + (IT) * 2048 + lane * 8;                           \
    _Pragma("unroll")                                                         \
    for (int nt_ = 0; nt_ < 4; ++nt_) {                                       \
      WH[nt_] = *(const bf16x8*)(fb_ + nt_ * 512);                            \
      if (!isv) WL[nt_] = *(const bf16x8*)(fb_ + 65536 + nt_ * 512);          \
    }                                                                         \
  }

#define MFMA_ITER(XA, XB, WH, WL)                                             \
  {                                                                           \
    u32 xh32_[4], xl32_[4];                                                   \
    _Pragma("unroll")                                                         \
    for (int p_ = 0; p_ < 4; ++p_) {                                          \
      const float f0_ = (p_ < 2) ? XA[2 * p_] : XB[2 * p_ - 4];               \
      const float f1_ = (p_ < 2) ? XA[2 * p_ + 1] : XB[2 * p_ - 3];           \
      const u32 u0_ = __builtin_bit_cast(u32, f0_);                           \
      const u32 u1_ = __builtin_bit_cast(u32, f1_);                           \
      xh32_[p_] = permhi(u1_, u0_);                                           \
      const float h0_ = __builtin_bit_cast(float, u0_ & 0xFFFF0000u);         \
      const float h1_ = __builtin_bit_cast(float, u1_ & 0xFFFF0000u);         \
      xl32_[p_] = permhi(__builtin_bit_cast(u32, f1_ - h1_),                  \
                         __builtin_bit_cast(u32, f0_ - h0_));                 \
    }                                                                         \
    bf16x8 xh_, xl_;                                                          \
    _Pragma("unroll")                                                         \
    for (int p_ = 0; p_ < 4; ++p_) {                                          \
      ((u32*)&xh_)[p_] = xh32_[p_];                                           \
      ((u32*)&xl_)[p_] = xl32_[p_];                                           \
    }                                                                         \
    _Pragma("unroll")                                                         \
    for (int nt_ = 0; nt_ < 4; ++nt_) {                                       \
      acc[nt_] = mfma16(xh_, WH[nt_], acc[nt_]);                              \
      if (!isv) {                                                             \
        acc[nt_] = mfma16(xh_, WL[nt_], acc[nt_]);                            \
        acc[nt_] = mfma16(xl_, WH[nt_], acc[nt_]);                            \
      }                                                                       \
    }                                                                         \
  }

  LOAD_ITER(xaA, xbA, whA, wlA, 0)
#pragma unroll
  for (int it2 = 0; it2 < 16; ++it2) {
    LOAD_ITER(xaB, xbB, whB, wlB, 2 * it2 + 1)
    MFMA_ITER(xaA, xbA, whA, wlA)
    if (it2 < 15) LOAD_ITER(xaA, xbA, whA, wlA, 2 * it2 + 2)
    MFMA_ITER(xaB, xbB, whB, wlB)
  }
#undef LOAD_ITER
#undef MFMA_ITER

  // epilogue: bias add + hi/lo store (q/k chunk-swizzled for attn LDS staging)
  const float* bias = (type == 0) ? bq : (type == 1) ? bk : bv;
#pragma unroll
  for (int nt = 0; nt < 4; ++nt) {
    const int col = nt * 16 + l15;
    const float bb = bias[col];
#pragma unroll
    for (int rr = 0; rr < 4; ++rr) {
      const int row = rb * 64 + w * 16 + g4 * 4 + rr;
      const float val = acc[nt][rr] + bb;
      const u16 h = f2bf(val);
      if (type < 2) {
        const int colS = ((((col >> 3) ^ (row & 7)) << 3) | (col & 7));
        u16* hiP = (type == 0) ? qhi : khi;
        u16* loP = (type == 0) ? qlo : klo;
        hiP[(size_t)row * HH + colS] = h;
        loP[(size_t)row * HH + colS] = f2bf(val - bf2f(h));
      } else {
        vt[(size_t)col * NTOK + row] = h;
      }
    }
  }
}

// ---------------------------------------------------------------------------
// Flash attention (roles swapped), block-cooperative:
// block = (b, TW 64-row tile, split s of 8 j-tiles x 64 cols). 4 waves, wave w
// owns rows TW*64 + w*16 .. +16. Q hi/lo staged (double-buffered) in LDS via
// VERBATIM copy of the already-swizzled global array; ds_reads XOR-decode
// exactly once. V prefetched to registers at loop top (latency hidden under
// QK^T+softmax). Swapped-operand QK^T: lane owns a full S row.
// ---------------------------------------------------------------------------
__global__ __launch_bounds__(256) void attn_kernel(
    const u16* __restrict__ qhi, const u16* __restrict__ qlo,
    const u16* __restrict__ khi, const u16* __restrict__ klo,
    const u16* __restrict__ vt, u16* __restrict__ Opart,
    float* __restrict__ ml)
{
  __shared__ __attribute__((aligned(16))) u16 qh_lds[2][64][64];
  __shared__ __attribute__((aligned(16))) u16 ql_lds[2][64][64];
  __shared__ __attribute__((aligned(16))) u16 plds[4][16][72];
  const int tid = threadIdx.x;
  const int lane = tid & 63;
  const int w = tid >> 6;
  const int l15 = lane & 15;
  const int g4 = lane >> 4;

  const int b = blockIdx.x >> 9;
  const int TW = (blockIdx.x >> 3) & 63;
  const int s = blockIdx.x & 7;
  const int ns = (TW + 8) >> 3;          // ceil((TW+1)/8)
  if (s >= ns) return;
  const int jt0 = s * 8;
  const int jt1 = (jt0 + 8 < TW + 1) ? jt0 + 8 : TW + 1;
  const int rowbase = TW * 64 + w * 16;

  // K fragments (roleQ = k-proj), swizzled addressing: chunk ^= (l15&7)
  bf16x8 kh[2], kl[2];
#pragma unroll
  for (int ksub = 0; ksub < 2; ++ksub) {
    const size_t ro = (size_t)(b * TT + rowbase + l15) * HH;
    const int ch = ((ksub * 4 + g4) ^ (l15 & 7)) * 8;
    kh[ksub] = *(const bf16x8*)(khi + ro + ch);
    kl[ksub] = *(const bf16x8*)(klo + ro + ch);
  }

  // stage j-tile jt into buffer buf: VERBATIM row copy (swizzle preserved)
  auto stage = [&](int buf, int jt) {
    const size_t gbase = (size_t)(b * TT + jt * 64) * HH;
    const int rsrc = (lane >> 3);
    const int csrc = (lane & 7) * 8;     // linear copy; swizzle lives in data
#pragma unroll
    for (int i = 0; i < 2; ++i) {
      const int r0 = w * 16 + i * 8;
      const size_t src = gbase + (size_t)(r0 + rsrc) * HH + csrc;
      gl_lds16(qhi + src, &qh_lds[buf][r0][0]);
      gl_lds16(qlo + src, &ql_lds[buf][r0][0]);
    }
  };

  float m = -INFINITY, lsum = 0.f;       // per-lane row i = rowbase + l15
  f32x4 O[4];
#pragma unroll
  for (int ht = 0; ht < 4; ++ht) O[ht] = (f32x4){0.f, 0.f, 0.f, 0.f};

  stage(0, jt0);
  __syncthreads();
  int cur = 0;
  for (int jt = jt0; jt < jt1; ++jt) {
    if (jt + 1 < jt1) stage(cur ^ 1, jt + 1);
    // ---- V prefetch to registers (independent; hides L2 latency) ----
    const int j0 = jt * 64;
    bf16x8 vf[8];
#pragma unroll
    for (int kt2 = 0; kt2 < 2; ++kt2)
#pragma unroll
      for (int ht = 0; ht < 4; ++ht)
        vf[kt2 * 4 + ht] = *(const bf16x8*)(vt + (size_t)(ht * 16 + l15) * NTOK +
                                            b * TT + j0 + kt2 * 32 + g4 * 8);
    // ---- QK^T (swapped): S[nt] cols i=l15, rows j = nt*16 + g4*4 + rr ----
    f32x4 S[4];
#pragma unroll
    for (int nt = 0; nt < 4; ++nt) S[nt] = (f32x4){0.f, 0.f, 0.f, 0.f};
#pragma unroll
    for (int nt = 0; nt < 4; ++nt) {
      const int row = nt * 16 + l15;
      const int c0 = (g4 ^ (l15 & 7)) * 8;
      const int c1 = ((4 + g4) ^ (l15 & 7)) * 8;
      const bf16x8 q0 = *(const bf16x8*)&qh_lds[cur][row][c0];
      const bf16x8 q1 = *(const bf16x8*)&qh_lds[cur][row][c1];
      const bf16x8 ql0 = *(const bf16x8*)&ql_lds[cur][row][c0];
      const bf16x8 ql1 = *(const bf16x8*)&ql_lds[cur][row][c1];
      S[nt] = mfma16(q0, kh[0], S[nt]);
      S[nt] = mfma16(q1, kh[1], S[nt]);
      S[nt] = mfma16(ql0, kh[0], S[nt]);
      S[nt] = mfma16(ql1, kh[1], S[nt]);
      S[nt] = mfma16(q0, kl[0], S[nt]);
      S[nt] = mfma16(q1, kl[1], S[nt]);
    }
    if (jt == TW) {  // diagonal tile: mask j > i
      const int ii = rowbase + l15;
#pragma unroll
      for (int nt = 0; nt < 4; ++nt)
#pragma unroll
        for (int rr = 0; rr < 4; ++rr) {
          const int jj = jt * 64 + nt * 16 + g4 * 4 + rr;
          if (jj > ii) S[nt][rr] = -INFINITY;
        }
    }
    // ---- online softmax: 16 in-lane values + 2 shuffles ----
    float tm = -INFINITY;
#pragma unroll
    for (int nt = 0; nt < 4; ++nt)
#pragma unroll
      for (int rr = 0; rr < 4; ++rr) tm = fmaxf(tm, S[nt][rr]);
    tm = fmaxf(tm, __shfl_xor(tm, 16));
    tm = fmaxf(tm, __shfl_xor(tm, 32));
    const float mnew = fmaxf(m, tm);
    const float sc = __expf(m - mnew);
    m = mnew;
    float ssum = 0.f;
#pragma unroll
    for (int nt = 0; nt < 4; ++nt)
#pragma unroll
      for (int rr = 0; rr < 4; ++rr) {
        const float p = __expf(S[nt][rr] - mnew);
        S[nt][rr] = p;
        ssum += p;
      }
    ssum += __shfl_xor(ssum, 16);
    ssum += __shfl_xor(ssum, 32);
    lsum = lsum * sc + ssum;
#pragma unroll
    for (int ht = 0; ht < 4; ++ht)
#pragma unroll
      for (int rr = 0; rr < 4; ++rr) O[ht][rr] *= sc;
    // ---- P -> wave-private LDS (packed bf16), re-layout for PV B-operand ----
#pragma unroll
    for (int nt = 0; nt < 4; ++nt) {
      *(u32*)&plds[w][l15][nt * 16 + g4 * 4] = cvtpk(S[nt][0], S[nt][1]);
      *(u32*)&plds[w][l15][nt * 16 + g4 * 4 + 2] = cvtpk(S[nt][2], S[nt][3]);
    }
    // ---- PV: A = prefetched v^T fragments, B = P^T from LDS ----
#pragma unroll
    for (int kt2 = 0; kt2 < 2; ++kt2) {
      const bf16x8 pf = *(const bf16x8*)&plds[w][l15][kt2 * 32 + g4 * 8];
#pragma unroll
      for (int ht = 0; ht < 4; ++ht)
        O[ht] = mfma16(vf[kt2 * 4 + ht], pf, O[ht]);
    }
    __syncthreads();
    cur ^= 1;
  }
  // epilogue: partials Opart[task][h=64][r=64] bf16; ml m/l per row
  const int task = blockIdx.x;
  u16* opb = Opart + (size_t)task * 4096;
#pragma unroll
  for (int ht = 0; ht < 4; ++ht)
#pragma unroll
    for (int rr = 0; rr < 4; ++rr)
      opb[(ht * 16 + g4 * 4 + rr) * 64 + w * 16 + l15] = f2bf(O[ht][rr]);
  if (g4 == 0) {
    ml[task * 64 + w * 16 + l15] = m;
    ml[NTASKS * 64 + task * 64 + w * 16 + l15] = lsum;
  }
}

// ---------------------------------------------------------------------------
// Combine: block per (b, TW, hq of 4): merge ns split partials for 64 rows x
// 16 h, normalize, LDS transpose, coalesced fp32 store. Grid 1024.
// ---------------------------------------------------------------------------
__global__ __launch_bounds__(256) void combine_kernel(
    const u16* __restrict__ Opart, const float* __restrict__ ml,
    float* __restrict__ out)
{
  __shared__ float lt[64][17];
  const int tid = threadIdx.x;
  const int b = blockIdx.x >> 8;
  const int rem = blockIdx.x & 255;
  const int TW = rem >> 2;
  const int hq = rem & 3;              // h-group of 16
  const int ns = (TW + 8) >> 3;
  const int tb = ((b << 6) | TW) * 8;  // task base
  const int ro = tid & 63;             // row
  const int hh4 = tid >> 6;            // 4 h-subgroups of 4
  const float* mb = ml;
  const float* lb = ml + NTASKS * 64;

  float M = -INFINITY;
  for (int ss = 0; ss < ns; ++ss)
    M = fmaxf(M, mb[(tb + ss) * 64 + ro]);
  float L = 0.f;
  float acc[4] = {0.f, 0.f, 0.f, 0.f};
  for (int ss = 0; ss < ns; ++ss) {
    const float e = __expf(mb[(tb + ss) * 64 + ro] - M);
    L += e * lb[(tb + ss) * 64 + ro];
    const u16* op = Opart + (size_t)(tb + ss) * 4096 +
                    (hq * 16 + hh4 * 4) * 64 + ro;
#pragma unroll
    for (int et = 0; et < 4; ++et) acc[et] += e * bf2f(op[et * 64]);
  }
  const float rL = 1.f / L;
#pragma unroll
  for (int et = 0; et < 4; ++et) lt[ro][hh4 * 4 + et] = acc[et] * rL;
  __syncthreads();
  const int hh = tid & 15;
  const int rq = tid >> 4;             // 16 rows per pass
#pragma unroll
  for (int pp = 0; pp < 4; ++pp) {
    const int r = pp * 16 + rq;
    out[(size_t)(b * TT + TW * 64 + r) * HH + hq * 16 + hh] = lt[r][hh];
  }
}

extern "C" void kernel_launch(void* const* d_in, const int* in_sizes, int n_in,
                              void* d_out, int out_size, void* d_ws, size_t ws_size,
                              hipStream_t stream) {
  (void)in_sizes; (void)n_in; (void)out_size; (void)ws_size;
  const float* x  = (const float*)d_in[0];
  const float* Wq = (const float*)d_in[1];
  const float* bq = (const float*)d_in[2];
  const float* Wk = (const float*)d_in[3];
  const float* bk = (const float*)d_in[4];
  const float* Wv = (const float*)d_in[5];
  const float* bv = (const float*)d_in[6];
  float* out = (float*)d_out;

  u16* ws   = (u16*)d_ws;
  u16* wpre = ws;                          // 5*65536 u16
  u16* qhi  = ws + 5 * 65536;
  u16* qlo  = qhi + (size_t)NTOK * HH;
  u16* khi  = qlo + (size_t)NTOK * HH;
  u16* klo  = khi + (size_t)NTOK * HH;
  u16* vt   = klo + (size_t)NTOK * HH;     // [64][NTOK]
  u16* Opart = vt + (size_t)NTOK * HH;     // NTASKS*4096 u16
  float* ml  = (float*)(Opart + (size_t)NTASKS * 4096);  // 2*NTASKS*64 f32

  prep_w<<<160, 256, 0, stream>>>(Wq, Wk, Wv, wpre);
  proj_kernel<<<768, 256, 0, stream>>>(x, bq, bk, bv, wpre,
                                       qhi, qlo, khi, klo, vt);
  attn_kernel<<<NTASKS, 256, 0, stream>>>(qhi, qlo, khi, klo, vt, Opart, ml);
  combine_kernel<<<1024, 256, 0, stream>>>(Opart, ml, out);
}

// Round 10
// 235.112 us; speedup vs baseline: 1.3763x; 1.0029x over previous
//
#include <hip/hip_runtime.h>
#include <hip/hip_bf16.h>

#define BB 4
#define TT 4096
#define NTOK (BB * TT)   // 16384
#define DD 1024
#define HH 64
#define NTASKS 2048      // 4 b x 64 TW x 8 s (some empty)

typedef __attribute__((ext_vector_type(8))) __bf16 bf16x8;
typedef __attribute__((ext_vector_type(8))) unsigned short ushort8;
typedef __attribute__((ext_vector_type(4))) float f32x4;
typedef __attribute__((ext_vector_type(4))) float f4;
typedef unsigned short u16;
typedef unsigned int u32;

__device__ __forceinline__ u16 f2bf(float f) {
  unsigned u = __builtin_bit_cast(unsigned, f);
  u += 0x7FFFu + ((u >> 16) & 1u);   // RNE
  return (u16)(u >> 16);
}
__device__ __forceinline__ float bf2f(u16 s) {
  unsigned u = ((unsigned)s) << 16;
  return __builtin_bit_cast(float, u);
}
__device__ __forceinline__ f32x4 mfma16(bf16x8 a, bf16x8 b, f32x4 c) {
  return __builtin_amdgcn_mfma_f32_16x16x32_bf16(a, b, c, 0, 0, 0);
}
__device__ __forceinline__ u32 cvtpk(float lo, float hi) {
  u32 r;
  asm("v_cvt_pk_bf16_f32 %0, %1, %2" : "=v"(r) : "v"(lo), "v"(hi));
  return r;
}
// pack upper-16s of two floats: (hi16(f1)<<16)|hi16(f0)  -- truncating bf16 pair
__device__ __forceinline__ u32 permhi(u32 u1, u32 u0) {
  return __builtin_amdgcn_perm(u1, u0, 0x07060302u);
}
__device__ __forceinline__ void gl_lds16(const u16* g, u16* l) {
  __builtin_amdgcn_global_load_lds(
      (const __attribute__((address_space(1))) u32*)(const void*)g,
      (__attribute__((address_space(3))) u32*)(void*)l, 16, 0, 0);
}

// ---------------------------------------------------------------------------
// prep_w: W (fp32) -> bf16 hi/lo in FRAGMENT-LINEAR order:
// [kt(16)][ksub(2)][nt(4)][lane(64)][e(8)] so proj's B-operand load is one
// coalesced dwordx4 per lane. frag elem: W[nt*16+(l&15)][kt*64+ksub*32+(l>>4)*8+e]
// Arrays: 0=Wq_hi 1=Wq_lo 2=Wk_hi 3=Wk_lo 4=Wv_hi, each 65536 u16.
// ---------------------------------------------------------------------------
__global__ __launch_bounds__(256) void prep_w(
    const float* __restrict__ Wq, const float* __restrict__ Wk,
    const float* __restrict__ Wv, u16* __restrict__ wpre)
{
  const int c = blockIdx.x * 256 + threadIdx.x;   // 40960 ushort8 chunks
  const int arr = c >> 13;
  const int rem = c & 8191;      // [kt][ksub][nt][lane]
  const int lane = rem & 63;
  const int nt = (rem >> 6) & 3;
  const int ksub = (rem >> 8) & 1;
  const int kt = rem >> 9;
  const float* W = (arr <= 1) ? Wq : (arr <= 3) ? Wk : Wv;
  const bool lo = (arr == 1) || (arr == 3);
  const int n = nt * 16 + (lane & 15);
  const int k0 = kt * 64 + ksub * 32 + (lane >> 4) * 8;
  const float* src = W + (size_t)n * DD + k0;
  ushort8 out;
#pragma unroll
  for (int e = 0; e < 8; ++e) {
    const float f = src[e];
    const u16 h = f2bf(f);
    out[e] = lo ? f2bf(f - bf2f(h)) : h;
  }
  *(ushort8*)(wpre + (size_t)arr * 65536 + (size_t)rem * 8) = out;
}

// ---------------------------------------------------------------------------
// Projection: barrier-free, LDS-free, SOFTWARE-PIPELINED. W via coalesced
// fragment-linear loads (L2-resident); x split hi/lo by truncation (v_perm).
// Register double-buffer A/B: loads for iteration it+1 are issued before the
// MFMAs of iteration it. __launch_bounds__(256,3): allow ~168 VGPR while
// keeping 3 blocks/CU. blockIdx = rowblock(256) + 256*type.
// q/k stores column-chunk-swizzled: chunk ^= (row&7).
// ---------------------------------------------------------------------------
__global__ __launch_bounds__(256, 3) void proj_kernel(
    const float* __restrict__ x,
    const float* __restrict__ bq, const float* __restrict__ bk,
    const float* __restrict__ bv, const u16* __restrict__ wpre,
    u16* __restrict__ qhi, u16* __restrict__ qlo,
    u16* __restrict__ khi, u16* __restrict__ klo,
    u16* __restrict__ vt)
{
  const int tid = threadIdx.x;
  const int w = tid >> 6;
  const int lane = tid & 63;
  const int l15 = lane & 15;
  const int g4 = lane >> 4;
  const int rb = blockIdx.x & 255;
  const int type = blockIdx.x >> 8;
  const bool isv = (type == 2);
  const u16* whiP = wpre + (size_t)((type == 0) ? 0 : (type == 1) ? 2 : 4) * 65536;
  const int mrow = rb * 64 + w * 16 + l15;
  const float* xrow = x + (size_t)mrow * DD;

  f32x4 acc[4];
#pragma unroll
  for (int i = 0; i < 4; ++i) acc[i] = (f32x4){0.f, 0.f, 0.f, 0.f};

  // named double-buffers (static allocation; no runtime indexing)
  f4 xaA, xbA, xaB, xbB;
  bf16x8 whA[4], wlA[4], whB[4], wlB[4];

#define LOAD_ITER(XA, XB, WH, WL, IT)                                         \
  {                                                                           \
    const float* xs_ = xrow + (IT) * 32 + g4 * 8;                             \
    XA = *(const f4*)xs_;                                                     \
    XB = *(const f4*)(xs_ + 4);                                               \
    const u16* fb_ = whiP + (IT) * 2048 + lane * 8;                           \
    _Pragma("unroll")                                                         \
    for (int nt_ = 0; nt_ < 4; ++nt_) {                                       \
      WH[nt_] = *(const bf16x8*)(fb_ + nt_ * 512);                            \
      if (!isv) WL[nt_] = *(const bf16x8*)(fb_ + 65536 + nt_ * 512);          \
    }                                                                         \
  }

#define MFMA_ITER(XA, XB, WH, WL)                                             \
  {                                                                           \
    u32 xh32_[4], xl32_[4];                                                   \
    _Pragma("unroll")                                                         \
    for (int p_ = 0; p_ < 4; ++p_) {                                          \
      const float f0_ = (p_ < 2) ? XA[2 * p_] : XB[2 * p_ - 4];               \
      const float f1_ = (p_ < 2) ? XA[2 * p_ + 1] : XB[2 * p_ - 3];           \
      const u32 u0_ = __builtin_bit_cast(u32, f0_);                           \
      const u32 u1_ = __builtin_bit_cast(u32, f1_);                           \
      xh32_[p_] = permhi(u1_, u0_);                                           \
      const float h0_ = __builtin_bit_cast(float, u0_ & 0xFFFF0000u);         \
      const float h1_ = __builtin_bit_cast(float, u1_ & 0xFFFF0000u);         \
      xl32_[p_] = permhi(__builtin_bit_cast(u32, f1_ - h1_),                  \
                         __builtin_bit_cast(u32, f0_ - h0_));                 \
    }                                                                         \
    bf16x8 xh_, xl_;                                                          \
    _Pragma("unroll")                                                         \
    for (int p_ = 0; p_ < 4; ++p_) {                                          \
      ((u32*)&xh_)[p_] = xh32_[p_];                                           \
      ((u32*)&xl_)[p_] = xl32_[p_];                                           \
    }                                                                         \
    _Pragma("unroll")                                                         \
    for (int nt_ = 0; nt_ < 4; ++nt_) {                                       \
      acc[nt_] = mfma16(xh_, WH[nt_], acc[nt_]);                              \
      if (!isv) {                                                             \
        acc[nt_] = mfma16(xh_, WL[nt_], acc[nt_]);                            \
        acc[nt_] = mfma16(xl_, WH[nt_], acc[nt_]);                            \
      }                                                                       \
    }                                                                         \
  }

  LOAD_ITER(xaA, xbA, whA, wlA, 0)
#pragma unroll
  for (int it2 = 0; it2 < 16; ++it2) {
    LOAD_ITER(xaB, xbB, whB, wlB, 2 * it2 + 1)
    MFMA_ITER(xaA, xbA, whA, wlA)
    if (it2 < 15) LOAD_ITER(xaA, xbA, whA, wlA, 2 * it2 + 2)
    MFMA_ITER(xaB, xbB, whB, wlB)
  }
#undef LOAD_ITER
#undef MFMA_ITER

  // epilogue: bias add + hi/lo store (q/k chunk-swizzled for attn LDS staging)
  const float* bias = (type == 0) ? bq : (type == 1) ? bk : bv;
#pragma unroll
  for (int nt = 0; nt < 4; ++nt) {
    const int col = nt * 16 + l15;
    const float bb = bias[col];
#pragma unroll
    for (int rr = 0; rr < 4; ++rr) {
      const int row = rb * 64 + w * 16 + g4 * 4 + rr;
      const float val = acc[nt][rr] + bb;
      const u16 h = f2bf(val);
      if (type < 2) {
        const int colS = ((((col >> 3) ^ (row & 7)) << 3) | (col & 7));
        u16* hiP = (type == 0) ? qhi : khi;
        u16* loP = (type == 0) ? qlo : klo;
        hiP[(size_t)row * HH + colS] = h;
        loP[(size_t)row * HH + colS] = f2bf(val - bf2f(h));
      } else {
        vt[(size_t)col * NTOK + row] = h;
      }
    }
  }
}

// ---------------------------------------------------------------------------
// Flash attention (roles swapped), block-cooperative:
// block = (b, TW 64-row tile, split s of 8 j-tiles x 64 cols). 4 waves, wave w
// owns rows TW*64 + w*16 .. +16. Q hi/lo staged (double-buffered) in LDS via
// VERBATIM copy of the already-swizzled global array; ds_reads XOR-decode
// exactly once. V prefetched to registers. P redistribution for PV is done
// IN-REGISTER via shuffles (no LDS): lane (g4,l15) word p of the kt2 fragment
// = w32[kt2*2+(g4>>1)][p&1] fetched from lane ((g4&1)*2+(p>>1))*16+l15.
// LDS = 32768 B -> up to 5 blocks/CU; __launch_bounds__(256,4) caps VGPR 128.
// ---------------------------------------------------------------------------
__global__ __launch_bounds__(256, 4) void attn_kernel(
    const u16* __restrict__ qhi, const u16* __restrict__ qlo,
    const u16* __restrict__ khi, const u16* __restrict__ klo,
    const u16* __restrict__ vt, u16* __restrict__ Opart,
    float* __restrict__ ml)
{
  __shared__ __attribute__((aligned(16))) u16 qh_lds[2][64][64];
  __shared__ __attribute__((aligned(16))) u16 ql_lds[2][64][64];
  const int tid = threadIdx.x;
  const int lane = tid & 63;
  const int w = tid >> 6;
  const int l15 = lane & 15;
  const int g4 = lane >> 4;

  const int b = blockIdx.x >> 9;
  const int TW = (blockIdx.x >> 3) & 63;
  const int s = blockIdx.x & 7;
  const int ns = (TW + 8) >> 3;          // ceil((TW+1)/8)
  if (s >= ns) return;
  const int jt0 = s * 8;
  const int jt1 = (jt0 + 8 < TW + 1) ? jt0 + 8 : TW + 1;
  const int rowbase = TW * 64 + w * 16;

  // K fragments (roleQ = k-proj), swizzled addressing: chunk ^= (l15&7)
  bf16x8 kh[2], kl[2];
#pragma unroll
  for (int ksub = 0; ksub < 2; ++ksub) {
    const size_t ro = (size_t)(b * TT + rowbase + l15) * HH;
    const int ch = ((ksub * 4 + g4) ^ (l15 & 7)) * 8;
    kh[ksub] = *(const bf16x8*)(khi + ro + ch);
    kl[ksub] = *(const bf16x8*)(klo + ro + ch);
  }

  // stage j-tile jt into buffer buf: VERBATIM row copy (swizzle preserved)
  auto stage = [&](int buf, int jt) {
    const size_t gbase = (size_t)(b * TT + jt * 64) * HH;
    const int rsrc = (lane >> 3);
    const int csrc = (lane & 7) * 8;     // linear copy; swizzle lives in data
#pragma unroll
    for (int i = 0; i < 2; ++i) {
      const int r0 = w * 16 + i * 8;
      const size_t src = gbase + (size_t)(r0 + rsrc) * HH + csrc;
      gl_lds16(qhi + src, &qh_lds[buf][r0][0]);
      gl_lds16(qlo + src, &ql_lds[buf][r0][0]);
    }
  };

  float m = -INFINITY, lsum = 0.f;       // per-lane row i = rowbase + l15
  f32x4 O[4];
#pragma unroll
  for (int ht = 0; ht < 4; ++ht) O[ht] = (f32x4){0.f, 0.f, 0.f, 0.f};

  stage(0, jt0);
  __syncthreads();
  int cur = 0;
  for (int jt = jt0; jt < jt1; ++jt) {
    if (jt + 1 < jt1) stage(cur ^ 1, jt + 1);
    // ---- V prefetch to registers (independent; hides L2 latency) ----
    const int j0 = jt * 64;
    bf16x8 vf[8];
#pragma unroll
    for (int kt2 = 0; kt2 < 2; ++kt2)
#pragma unroll
      for (int ht = 0; ht < 4; ++ht)
        vf[kt2 * 4 + ht] = *(const bf16x8*)(vt + (size_t)(ht * 16 + l15) * NTOK +
                                            b * TT + j0 + kt2 * 32 + g4 * 8);
    // ---- QK^T (swapped): S[nt] cols i=l15, rows j = nt*16 + g4*4 + rr ----
    f32x4 S[4];
#pragma unroll
    for (int nt = 0; nt < 4; ++nt) S[nt] = (f32x4){0.f, 0.f, 0.f, 0.f};
#pragma unroll
    for (int nt = 0; nt < 4; ++nt) {
      const int row = nt * 16 + l15;
      const int c0 = (g4 ^ (l15 & 7)) * 8;
      const int c1 = ((4 + g4) ^ (l15 & 7)) * 8;
      const bf16x8 q0 = *(const bf16x8*)&qh_lds[cur][row][c0];
      const bf16x8 q1 = *(const bf16x8*)&qh_lds[cur][row][c1];
      const bf16x8 ql0 = *(const bf16x8*)&ql_lds[cur][row][c0];
      const bf16x8 ql1 = *(const bf16x8*)&ql_lds[cur][row][c1];
      S[nt] = mfma16(q0, kh[0], S[nt]);
      S[nt] = mfma16(q1, kh[1], S[nt]);
      S[nt] = mfma16(ql0, kh[0], S[nt]);
      S[nt] = mfma16(ql1, kh[1], S[nt]);
      S[nt] = mfma16(q0, kl[0], S[nt]);
      S[nt] = mfma16(q1, kl[1], S[nt]);
    }
    if (jt == TW) {  // diagonal tile: mask j > i
      const int ii = rowbase + l15;
#pragma unroll
      for (int nt = 0; nt < 4; ++nt)
#pragma unroll
        for (int rr = 0; rr < 4; ++rr) {
          const int jj = jt * 64 + nt * 16 + g4 * 4 + rr;
          if (jj > ii) S[nt][rr] = -INFINITY;
        }
    }
    // ---- online softmax: 16 in-lane values + 2 shuffles ----
    float tm = -INFINITY;
#pragma unroll
    for (int nt = 0; nt < 4; ++nt)
#pragma unroll
      for (int rr = 0; rr < 4; ++rr) tm = fmaxf(tm, S[nt][rr]);
    tm = fmaxf(tm, __shfl_xor(tm, 16));
    tm = fmaxf(tm, __shfl_xor(tm, 32));
    const float mnew = fmaxf(m, tm);
    const float sc = __expf(m - mnew);
    m = mnew;
    float ssum = 0.f;
#pragma unroll
    for (int nt = 0; nt < 4; ++nt)
#pragma unroll
      for (int rr = 0; rr < 4; ++rr) {
        const float p = __expf(S[nt][rr] - mnew);
        S[nt][rr] = p;
        ssum += p;
      }
    ssum += __shfl_xor(ssum, 16);
    ssum += __shfl_xor(ssum, 32);
    lsum = lsum * sc + ssum;
#pragma unroll
    for (int ht = 0; ht < 4; ++ht)
#pragma unroll
      for (int rr = 0; rr < 4; ++rr) O[ht][rr] *= sc;
    // ---- P -> bf16 pairs, redistributed IN-REGISTER via shuffles ----
    u32 w32[4][2];
#pragma unroll
    for (int nt = 0; nt < 4; ++nt) {
      w32[nt][0] = cvtpk(S[nt][0], S[nt][1]);
      w32[nt][1] = cvtpk(S[nt][2], S[nt][3]);
    }
    const int src01 = ((g4 & 1) * 2) * 16 + l15;      // words p=0,1
    const int src23 = ((g4 & 1) * 2 + 1) * 16 + l15;  // words p=2,3
    const bool hi2 = (g4 >= 2);
#pragma unroll
    for (int kt2 = 0; kt2 < 2; ++kt2) {
      u32 W[4];
#pragma unroll
      for (int p = 0; p < 4; ++p) {
        const int src = (p < 2) ? src01 : src23;
        const u32 va = (u32)__shfl((int)w32[kt2 * 2][p & 1], src);
        const u32 vb = (u32)__shfl((int)w32[kt2 * 2 + 1][p & 1], src);
        W[p] = hi2 ? vb : va;
      }
      bf16x8 pf;
      ((u32*)&pf)[0] = W[0];
      ((u32*)&pf)[1] = W[1];
      ((u32*)&pf)[2] = W[2];
      ((u32*)&pf)[3] = W[3];
      // ---- PV: A = prefetched v^T fragments, B = P^T fragment ----
#pragma unroll
      for (int ht = 0; ht < 4; ++ht)
        O[ht] = mfma16(vf[kt2 * 4 + ht], pf, O[ht]);
    }
    __syncthreads();
    cur ^= 1;
  }
  // epilogue: partials Opart[task][h=64][r=64] bf16; ml m/l per row
  const int task = blockIdx.x;
  u16* opb = Opart + (size_t)task * 4096;
#pragma unroll
  for (int ht = 0; ht < 4; ++ht)
#pragma unroll
    for (int rr = 0; rr < 4; ++rr)
      opb[(ht * 16 + g4 * 4 + rr) * 64 + w * 16 + l15] = f2bf(O[ht][rr]);
  if (g4 == 0) {
    ml[task * 64 + w * 16 + l15] = m;
    ml[NTASKS * 64 + task * 64 + w * 16 + l15] = lsum;
  }
}

// ---------------------------------------------------------------------------
// Combine: block per (b, TW, hq of 4): merge ns split partials for 64 rows x
// 16 h, normalize, LDS transpose, coalesced fp32 store. Grid 1024.
// ---------------------------------------------------------------------------
__global__ __launch_bounds__(256) void combine_kernel(
    const u16* __restrict__ Opart, const float* __restrict__ ml,
    float* __restrict__ out)
{
  __shared__ float lt[64][17];
  const int tid = threadIdx.x;
  const int b = blockIdx.x >> 8;
  const int rem = blockIdx.x & 255;
  const int TW = rem >> 2;
  const int hq = rem & 3;              // h-group of 16
  const int ns = (TW + 8) >> 3;
  const int tb = ((b << 6) | TW) * 8;  // task base
  const int ro = tid & 63;             // row
  const int hh4 = tid >> 6;            // 4 h-subgroups of 4
  const float* mb = ml;
  const float* lb = ml + NTASKS * 64;

  float M = -INFINITY;
  for (int ss = 0; ss < ns; ++ss)
    M = fmaxf(M, mb[(tb + ss) * 64 + ro]);
  float L = 0.f;
  float acc[4] = {0.f, 0.f, 0.f, 0.f};
  for (int ss = 0; ss < ns; ++ss) {
    const float e = __expf(mb[(tb + ss) * 64 + ro] - M);
    L += e * lb[(tb + ss) * 64 + ro];
    const u16* op = Opart + (size_t)(tb + ss) * 4096 +
                    (hq * 16 + hh4 * 4) * 64 + ro;
#pragma unroll
    for (int et = 0; et < 4; ++et) acc[et] += e * bf2f(op[et * 64]);
  }
  const float rL = 1.f / L;
#pragma unroll
  for (int et = 0; et < 4; ++et) lt[ro][hh4 * 4 + et] = acc[et] * rL;
  __syncthreads();
  const int hh = tid & 15;
  const int rq = tid >> 4;             // 16 rows per pass
#pragma unroll
  for (int pp = 0; pp < 4; ++pp) {
    const int r = pp * 16 + rq;
    out[(size_t)(b * TT + TW * 64 + r) * HH + hq * 16 + hh] = lt[r][hh];
  }
}

extern "C" void kernel_launch(void* const* d_in, const int* in_sizes, int n_in,
                              void* d_out, int out_size, void* d_ws, size_t ws_size,
                              hipStream_t stream) {
  (void)in_sizes; (void)n_in; (void)out_size; (void)ws_size;
  const float* x  = (const float*)d_in[0];
  const float* Wq = (const float*)d_in[1];
  const float* bq = (const float*)d_in[2];
  const float* Wk = (const float*)d_in[3];
  const float* bk = (const float*)d_in[4];
  const float* Wv = (const float*)d_in[5];
  const float* bv = (const float*)d_in[6];
  float* out = (float*)d_out;

  u16* ws   = (u16*)d_ws;
  u16* wpre = ws;                          // 5*65536 u16
  u16* qhi  = ws + 5 * 65536;
  u16* qlo  = qhi + (size_t)NTOK * HH;
  u16* khi  = qlo + (size_t)NTOK * HH;
  u16* klo  = khi + (size_t)NTOK * HH;
  u16* vt   = klo + (size_t)NTOK * HH;     // [64][NTOK]
  u16* Opart = vt + (size_t)NTOK * HH;     // NTASKS*4096 u16
  float* ml  = (float*)(Opart + (size_t)NTASKS * 4096);  // 2*NTASKS*64 f32

  prep_w<<<160, 256, 0, stream>>>(Wq, Wk, Wv, wpre);
  proj_kernel<<<768, 256, 0, stream>>>(x, bq, bk, bv, wpre,
                                       qhi, qlo, khi, klo, vt);
  attn_kernel<<<NTASKS, 256, 0, stream>>>(qhi, qlo, khi, klo, vt, Opart, ml);
  combine_kernel<<<1024, 256, 0, stream>>>(Opart, ml, out);
}